// Round 7
// baseline (53.480 us; speedup 1.0000x reference)
//
#include <hip/hip_runtime.h>
#include <math.h>

#define NT 256
#define NBSPLIT 8
#define NB (16 / NBSPLIT)   // = 2: one batch PAIR per thread, fully unrolled
#define NSWEEPS 4

__device__ __forceinline__ float fsqrt_(float x) { return __builtin_amdgcn_sqrtf(x); }
__device__ __forceinline__ float frcp_(float x)  { return __builtin_amdgcn_rcpf(x); }
__device__ __forceinline__ float frsq_(float x)  { return __builtin_amdgcn_rsqf(x); }

// Cyclic-Jacobi rotation, 3-transcendental form (was 4):
// t = 2a*sign(h) / (|h| + sqrt(h^2+4a^2)), c = rsq(1+t^2), s = t*c.
// Same rotation as the tau-form (numerator/denominator scaled by 2|a|);
// at h==0 the sign of t may differ from the old form — harmless, R is
// invariant to V column sign/order.
__device__ __forceinline__ void jrot(float& app, float& aqq, float& apq,
                                     float& arp, float& arq,
                                     float& vp0, float& vp1, float& vp2,
                                     float& vq0, float& vq1, float& vq2)
{
    float a = apq;
    float scale = fabsf(app) + fabsf(aqq);
    if (fabsf(a) > 1e-12f * scale + 1e-35f) {
        float h = aqq - app;
        float r = fsqrt_(fmaf(h, h, 4.0f * a * a));
        float den = fabsf(h) + r;
        float t2a = (h >= 0.0f) ? 2.0f * a : -2.0f * a;
        float t = t2a * frcp_(den);
        float c = frsq_(fmaf(t, t, 1.0f));
        float s = t * c;
        app -= t * a;
        aqq += t * a;
        apq = 0.0f;
        float rp = arp, rq = arq;
        arp = c * rp - s * rq;
        arq = s * rp + c * rq;
        float x, y;
        x = vp0; y = vq0; vp0 = c * x - s * y; vq0 = s * x + c * y;
        x = vp1; y = vq1; vp1 = c * x - s * y; vq1 = s * x + c * y;
        x = vp2; y = vq2; vp2 = c * x - s * y; vq2 = s * x + c * y;
    }
}

// maxd==6 specialized, 2-way batch ILP. One thread = one vertex x 2 batches,
// the two chains fully interleaved in straight-line code (independent dags:
// the scheduler hides each chain's trans/L2 latency under the other).
// Rationale: VGPR 65..128 is a flat 4-waves/SIMD plateau (m68/m69 steps at
// 64/128), so spend the 112->128 headroom on ILP, not on (unreachable)
// occupancy. NO launch_bounds min-waves pin (rounds 4/5: catastrophic spill).
//  - tevT row in LDS [18][NT], thread-private column, conflict- and
//    barrier-free. tevw never loaded (== w * tevT, folded).
//  - U never materialized: R = A*W, W = V diag(is, det-fixed at argmax) V^T.
//  - pass 2 re-gathers edges from L1/L2.
__global__ __launch_bounds__(NT) void arap_fused6(
    const float* __restrict__ pred,      // (B, 3, n)
    const int*   __restrict__ adj_idx,   // (n, 6)
    const float* __restrict__ adj_w,     // (n, 6)
    const float* __restrict__ tevT,      // (n, 3, 6)
    float* __restrict__ partials,        // (B, nblk_x)
    int n, int nblk_x)
{
    __shared__ float tvs[18][NT];
    __shared__ float sm[NT / 64][NB];

    const int tid = threadIdx.x;
    const int v = blockIdx.x * NT + tid;
    const bool active = (v < n);
    const int vc = active ? v : 0;
    const int b0 = blockIdx.y * NB;

    int   jo[6];
    float wgt[6];
    {
        const int2* ai = (const int2*)(adj_idx + (size_t)vc * 6);
        int2 q0 = ai[0], q1 = ai[1], q2 = ai[2];
        jo[0] = q0.x; jo[1] = q0.y; jo[2] = q1.x;
        jo[3] = q1.y; jo[4] = q2.x; jo[5] = q2.y;
        const float2* aw = (const float2*)(adj_w + (size_t)vc * 6);
        float2 w0 = aw[0], w1 = aw[1], w2 = aw[2];
        wgt[0] = w0.x; wgt[1] = w0.y; wgt[2] = w1.x;
        wgt[3] = w1.y; wgt[4] = w2.x; wgt[5] = w2.y;
        const float2* tv = (const float2*)(tevT + (size_t)vc * 18);
        #pragma unroll
        for (int i = 0; i < 9; ++i) {
            float2 t = tv[i];
            tvs[2 * i][tid]     = t.x;
            tvs[2 * i + 1][tid] = t.y;
        }
        // no __syncthreads: each thread only reads its own column
    }

    const int lane = tid & 63, wid = tid >> 6;

    const float* __restrict__ pA = pred + (size_t)b0 * 3 * n;       // batch b0
    const float* __restrict__ pB = pA + (size_t)3 * n;              // batch b0+1

    const float pax = pA[vc], pay = pA[n + vc], paz = pA[2 * n + vc];
    const float pbx = pB[vc], pby = pB[n + vc], pbz = pB[2 * n + vc];

    // ---- Pass 1 (both chains): A = 1000 * pred_ev @ (w * tevT^T) ----
    float A00 = 0.f, A01 = 0.f, A02 = 0.f, A10 = 0.f, A11 = 0.f, A12 = 0.f,
          A20 = 0.f, A21 = 0.f, A22 = 0.f;
    float B00 = 0.f, B01 = 0.f, B02 = 0.f, B10 = 0.f, B11 = 0.f, B12 = 0.f,
          B20 = 0.f, B21 = 0.f, B22 = 0.f;
    #pragma unroll
    for (int k = 0; k < 6; ++k) {
        int j = jo[k];
        float t0 = tvs[k][tid], t1 = tvs[6 + k][tid], t2 = tvs[12 + k][tid];
        float w = wgt[k];
        float ax = pA[j] - pax, ay = pA[n + j] - pay, az = pA[2 * n + j] - paz;
        float bx = pB[j] - pbx, by = pB[n + j] - pby, bz = pB[2 * n + j] - pbz;
        float fax = w * ax, fay = w * ay, faz = w * az;
        float fbx = w * bx, fby = w * by, fbz = w * bz;
        A00 += fax * t0; A01 += fax * t1; A02 += fax * t2;
        A10 += fay * t0; A11 += fay * t1; A12 += fay * t2;
        A20 += faz * t0; A21 += faz * t1; A22 += faz * t2;
        B00 += fbx * t0; B01 += fbx * t1; B02 += fbx * t2;
        B10 += fby * t0; B11 += fby * t1; B12 += fby * t2;
        B20 += fbz * t0; B21 += fbz * t1; B22 += fbz * t2;
    }
    const float stab = 1000.0f;
    A00 *= stab; A01 *= stab; A02 *= stab;
    A10 *= stab; A11 *= stab; A12 *= stab;
    A20 *= stab; A21 *= stab; A22 *= stab;
    B00 *= stab; B01 *= stab; B02 *= stab;
    B10 *= stab; B11 *= stab; B12 *= stab;
    B20 *= stab; B21 *= stab; B22 *= stab;

    // ---- M = A^T A, both chains ----
    float ma00 = A00 * A00 + A10 * A10 + A20 * A20;
    float ma01 = A00 * A01 + A10 * A11 + A20 * A21;
    float ma02 = A00 * A02 + A10 * A12 + A20 * A22;
    float ma11 = A01 * A01 + A11 * A11 + A21 * A21;
    float ma12 = A01 * A02 + A11 * A12 + A21 * A22;
    float ma22 = A02 * A02 + A12 * A12 + A22 * A22;
    float mb00 = B00 * B00 + B10 * B10 + B20 * B20;
    float mb01 = B00 * B01 + B10 * B11 + B20 * B21;
    float mb02 = B00 * B02 + B10 * B12 + B20 * B22;
    float mb11 = B01 * B01 + B11 * B11 + B21 * B21;
    float mb12 = B01 * B02 + B11 * B12 + B21 * B22;
    float mb22 = B02 * B02 + B12 * B12 + B22 * B22;

    // ---- interleaved dual Jacobi ----
    float va00 = 1.f, va01 = 0.f, va02 = 0.f;
    float va10 = 0.f, va11 = 1.f, va12 = 0.f;
    float va20 = 0.f, va21 = 0.f, va22 = 1.f;
    float vb00 = 1.f, vb01 = 0.f, vb02 = 0.f;
    float vb10 = 0.f, vb11 = 1.f, vb12 = 0.f;
    float vb20 = 0.f, vb21 = 0.f, vb22 = 1.f;
    #pragma unroll
    for (int sweep = 0; sweep < NSWEEPS; ++sweep) {
        jrot(ma00, ma11, ma01, ma02, ma12, va00, va10, va20, va01, va11, va21);
        jrot(mb00, mb11, mb01, mb02, mb12, vb00, vb10, vb20, vb01, vb11, vb21);
        jrot(ma00, ma22, ma02, ma01, ma12, va00, va10, va20, va02, va12, va22);
        jrot(mb00, mb22, mb02, mb01, mb12, vb00, vb10, vb20, vb02, vb12, vb22);
        jrot(ma11, ma22, ma12, ma01, ma02, va01, va11, va21, va02, va12, va22);
        jrot(mb11, mb22, mb12, mb01, mb02, vb01, vb11, vb21, vb02, vb12, vb22);
    }

    // ---- is/det/W/R, chain A ----
    float r00a, r01a, r02a, r10a, r11a, r12a, r20a, r21a, r22a;
    {
        float is0 = frsq_(fmaxf(ma00, 1e-6f));
        float is1 = frsq_(fmaxf(ma11, 1e-6f));
        float is2 = frsq_(fmaxf(ma22, 1e-6f));
        float detA = A00 * (A11 * A22 - A21 * A12)
                   - A10 * (A01 * A22 - A21 * A02)
                   + A20 * (A01 * A12 - A11 * A02);
        float dd = detA * is0 * is1 * is2;
        bool c2 = (ma22 >= ma00) && (ma22 >= ma11);
        bool c1 = !c2 && (ma11 >= ma00);
        bool c0 = !c2 && !c1;
        is0 = c0 ? is0 * dd : is0;
        is1 = c1 ? is1 * dd : is1;
        is2 = c2 ? is2 * dd : is2;
        float w00 = is0 * va00 * va00 + is1 * va01 * va01 + is2 * va02 * va02;
        float w01 = is0 * va00 * va10 + is1 * va01 * va11 + is2 * va02 * va12;
        float w02 = is0 * va00 * va20 + is1 * va01 * va21 + is2 * va02 * va22;
        float w11 = is0 * va10 * va10 + is1 * va11 * va11 + is2 * va12 * va12;
        float w12 = is0 * va10 * va20 + is1 * va11 * va21 + is2 * va12 * va22;
        float w22 = is0 * va20 * va20 + is1 * va21 * va21 + is2 * va22 * va22;
        r00a = A00 * w00 + A01 * w01 + A02 * w02;
        r01a = A00 * w01 + A01 * w11 + A02 * w12;
        r02a = A00 * w02 + A01 * w12 + A02 * w22;
        r10a = A10 * w00 + A11 * w01 + A12 * w02;
        r11a = A10 * w01 + A11 * w11 + A12 * w12;
        r12a = A10 * w02 + A11 * w12 + A12 * w22;
        r20a = A20 * w00 + A21 * w01 + A22 * w02;
        r21a = A20 * w01 + A21 * w11 + A22 * w12;
        r22a = A20 * w02 + A21 * w12 + A22 * w22;
    }
    // ---- is/det/W/R, chain B ----
    float r00b, r01b, r02b, r10b, r11b, r12b, r20b, r21b, r22b;
    {
        float is0 = frsq_(fmaxf(mb00, 1e-6f));
        float is1 = frsq_(fmaxf(mb11, 1e-6f));
        float is2 = frsq_(fmaxf(mb22, 1e-6f));
        float detB = B00 * (B11 * B22 - B21 * B12)
                   - B10 * (B01 * B22 - B21 * B02)
                   + B20 * (B01 * B12 - B11 * B02);
        float dd = detB * is0 * is1 * is2;
        bool c2 = (mb22 >= mb00) && (mb22 >= mb11);
        bool c1 = !c2 && (mb11 >= mb00);
        bool c0 = !c2 && !c1;
        is0 = c0 ? is0 * dd : is0;
        is1 = c1 ? is1 * dd : is1;
        is2 = c2 ? is2 * dd : is2;
        float w00 = is0 * vb00 * vb00 + is1 * vb01 * vb01 + is2 * vb02 * vb02;
        float w01 = is0 * vb00 * vb10 + is1 * vb01 * vb11 + is2 * vb02 * vb12;
        float w02 = is0 * vb00 * vb20 + is1 * vb01 * vb21 + is2 * vb02 * vb22;
        float w11 = is0 * vb10 * vb10 + is1 * vb11 * vb11 + is2 * vb12 * vb12;
        float w12 = is0 * vb10 * vb20 + is1 * vb11 * vb21 + is2 * vb12 * vb22;
        float w22 = is0 * vb20 * vb20 + is1 * vb21 * vb21 + is2 * vb22 * vb22;
        r00b = B00 * w00 + B01 * w01 + B02 * w02;
        r01b = B00 * w01 + B01 * w11 + B02 * w12;
        r02b = B00 * w02 + B01 * w12 + B02 * w22;
        r10b = B10 * w00 + B11 * w01 + B12 * w02;
        r11b = B10 * w01 + B11 * w11 + B12 * w12;
        r12b = B10 * w02 + B11 * w12 + B12 * w22;
        r20b = B20 * w00 + B21 * w01 + B22 * w02;
        r21b = B20 * w01 + B21 * w11 + B22 * w12;
        r22b = B20 * w02 + B21 * w12 + B22 * w22;
    }

    // ---- Pass 2 (both chains): energy, edges re-gathered (L1/L2) ----
    float nrgA = 0.0f, nrgB = 0.0f;
    #pragma unroll
    for (int k = 0; k < 6; ++k) {
        int j = jo[k];
        float t0 = tvs[k][tid], t1 = tvs[6 + k][tid], t2 = tvs[12 + k][tid];
        float ax = pA[j] - pax, ay = pA[n + j] - pay, az = pA[2 * n + j] - paz;
        float bx = pB[j] - pbx, by = pB[n + j] - pby, bz = pB[2 * n + j] - pbz;
        float qa0 = r00a * t0 + r01a * t1 + r02a * t2;
        float qa1 = r10a * t0 + r11a * t1 + r12a * t2;
        float qa2 = r20a * t0 + r21a * t1 + r22a * t2;
        float qb0 = r00b * t0 + r01b * t1 + r02b * t2;
        float qb1 = r10b * t0 + r11b * t1 + r12b * t2;
        float qb2 = r20b * t0 + r21b * t1 + r22b * t2;
        float dax = ax - qa0, day = ay - qa1, daz = az - qa2;
        float dbx = bx - qb0, dby = by - qb1, dbz = bz - qb2;
        float w = wgt[k];
        nrgA += w * fsqrt_(dax * dax + day * day + daz * daz);
        nrgB += w * fsqrt_(dbx * dbx + dby * dby + dbz * dbz);
    }
    float valA = active ? fminf(nrgA, 1.0f) : 0.0f;
    float valB = active ? fminf(nrgB, 1.0f) : 0.0f;

    #pragma unroll
    for (int off = 32; off > 0; off >>= 1) {
        valA += __shfl_down(valA, off, 64);
        valB += __shfl_down(valB, off, 64);
    }
    if (lane == 0) { sm[wid][0] = valA; sm[wid][1] = valB; }

    __syncthreads();
    if (tid < NB) {
        float s = 0.0f;
        #pragma unroll
        for (int w = 0; w < NT / 64; ++w) s += sm[w][tid];
        partials[(size_t)(b0 + tid) * nblk_x + blockIdx.x] = s;
    }
}

// ---------------- generic fallback ----------------
__global__ __launch_bounds__(NT) void arap_main(
    const float* __restrict__ pred, const int* __restrict__ adj_idx,
    const float* __restrict__ adj_w, const float* __restrict__ tevT,
    const float* __restrict__ tevw, float* __restrict__ partials,
    int n, int maxd, int nblk_x)
{
    const int b = blockIdx.y;
    const float* __restrict__ predb = pred + (size_t)b * 3 * n;
    float local = 0.0f;

    for (int v = blockIdx.x * NT + threadIdx.x; v < n; v += nblk_x * NT) {
        const float p0x = predb[v];
        const float p0y = predb[n + v];
        const float p0z = predb[2 * n + v];

        float a00 = 0.f, a01 = 0.f, a02 = 0.f;
        float a10 = 0.f, a11 = 0.f, a12 = 0.f;
        float a20 = 0.f, a21 = 0.f, a22 = 0.f;
        for (int k = 0; k < maxd; ++k) {
            int j = adj_idx[v * maxd + k];
            float ex = predb[j] - p0x;
            float ey = predb[n + j] - p0y;
            float ez = predb[2 * n + j] - p0z;
            const float* tw = tevw + ((size_t)v * maxd + k) * 3;
            float t0 = tw[0], t1 = tw[1], t2 = tw[2];
            a00 += ex * t0; a01 += ex * t1; a02 += ex * t2;
            a10 += ey * t0; a11 += ey * t1; a12 += ey * t2;
            a20 += ez * t0; a21 += ez * t1; a22 += ez * t2;
        }
        const float stab = 1000.0f;
        a00 *= stab; a01 *= stab; a02 *= stab;
        a10 *= stab; a11 *= stab; a12 *= stab;
        a20 *= stab; a21 *= stab; a22 *= stab;

        float m00 = a00 * a00 + a10 * a10 + a20 * a20;
        float m01 = a00 * a01 + a10 * a11 + a20 * a21;
        float m02 = a00 * a02 + a10 * a12 + a20 * a22;
        float m11 = a01 * a01 + a11 * a11 + a21 * a21;
        float m12 = a01 * a02 + a11 * a12 + a21 * a22;
        float m22 = a02 * a02 + a12 * a12 + a22 * a22;

        float v00 = 1.f, v01 = 0.f, v02 = 0.f;
        float v10 = 0.f, v11 = 1.f, v12 = 0.f;
        float v20 = 0.f, v21 = 0.f, v22 = 1.f;
        #pragma unroll
        for (int sweep = 0; sweep < NSWEEPS; ++sweep) {
            jrot(m00, m11, m01, m02, m12, v00, v10, v20, v01, v11, v21);
            jrot(m00, m22, m02, m01, m12, v00, v10, v20, v02, v12, v22);
            jrot(m11, m22, m12, m01, m02, v01, v11, v21, v02, v12, v22);
        }

        float is0 = frsq_(fmaxf(m00, 1e-6f));
        float is1 = frsq_(fmaxf(m11, 1e-6f));
        float is2 = frsq_(fmaxf(m22, 1e-6f));
        float detA = a00 * (a11 * a22 - a21 * a12)
                   - a10 * (a01 * a22 - a21 * a02)
                   + a20 * (a01 * a12 - a11 * a02);
        float dd = detA * is0 * is1 * is2;
        bool c2 = (m22 >= m00) && (m22 >= m11);
        bool c1 = !c2 && (m11 >= m00);
        bool c0 = !c2 && !c1;
        is0 = c0 ? is0 * dd : is0;
        is1 = c1 ? is1 * dd : is1;
        is2 = c2 ? is2 * dd : is2;

        float w00 = is0 * v00 * v00 + is1 * v01 * v01 + is2 * v02 * v02;
        float w01 = is0 * v00 * v10 + is1 * v01 * v11 + is2 * v02 * v12;
        float w02 = is0 * v00 * v20 + is1 * v01 * v21 + is2 * v02 * v22;
        float w11 = is0 * v10 * v10 + is1 * v11 * v11 + is2 * v12 * v12;
        float w12 = is0 * v10 * v20 + is1 * v11 * v21 + is2 * v12 * v22;
        float w22 = is0 * v20 * v20 + is1 * v21 * v21 + is2 * v22 * v22;

        float r00 = a00 * w00 + a01 * w01 + a02 * w02;
        float r01 = a00 * w01 + a01 * w11 + a02 * w12;
        float r02 = a00 * w02 + a01 * w12 + a02 * w22;
        float r10 = a10 * w00 + a11 * w01 + a12 * w02;
        float r11 = a10 * w01 + a11 * w11 + a12 * w12;
        float r12 = a10 * w02 + a11 * w12 + a12 * w22;
        float r20 = a20 * w00 + a21 * w01 + a22 * w02;
        float r21 = a20 * w01 + a21 * w11 + a22 * w12;
        float r22 = a20 * w02 + a21 * w12 + a22 * w22;

        float nrg = 0.0f;
        const float* tvb = tevT + (size_t)v * 3 * maxd;
        for (int k = 0; k < maxd; ++k) {
            int j = adj_idx[v * maxd + k];
            float w = adj_w[v * maxd + k];
            float ex = predb[j] - p0x;
            float ey = predb[n + j] - p0y;
            float ez = predb[2 * n + j] - p0z;
            float tv0 = tvb[k];
            float tv1 = tvb[maxd + k];
            float tv2 = tvb[2 * maxd + k];
            float q0 = r00 * tv0 + r01 * tv1 + r02 * tv2;
            float q1 = r10 * tv0 + r11 * tv1 + r12 * tv2;
            float q2 = r20 * tv0 + r21 * tv1 + r22 * tv2;
            float dx = ex - q0, dy = ey - q1, dz = ez - q2;
            nrg += w * fsqrt_(dx * dx + dy * dy + dz * dz);
        }
        local += fminf(nrg, 1.0f);
    }

    float val = local;
    for (int off = 32; off > 0; off >>= 1)
        val += __shfl_down(val, off, 64);
    __shared__ float smf[NT / 64];
    int lane = threadIdx.x & 63, wid = threadIdx.x >> 6;
    if (lane == 0) smf[wid] = val;
    __syncthreads();
    if (threadIdx.x == 0)
        partials[(size_t)b * nblk_x + blockIdx.x] = smf[0] + smf[1] + smf[2] + smf[3];
}

__global__ __launch_bounds__(NT) void arap_reduce(
    const float* __restrict__ partials, float* __restrict__ out,
    int nblk_x, float inv_n)
{
    int b = blockIdx.x;
    float val = 0.0f;
    for (int i = threadIdx.x; i < nblk_x; i += NT)
        val += partials[(size_t)b * nblk_x + i];
    for (int off = 32; off > 0; off >>= 1)
        val += __shfl_down(val, off, 64);
    __shared__ float smf[NT / 64];
    int lane = threadIdx.x & 63, wid = threadIdx.x >> 6;
    if (lane == 0) smf[wid] = val;
    __syncthreads();
    if (threadIdx.x == 0)
        out[b] = (smf[0] + smf[1] + smf[2] + smf[3]) * inv_n;
}

extern "C" void kernel_launch(void* const* d_in, const int* in_sizes, int n_in,
                              void* d_out, int out_size, void* d_ws, size_t ws_size,
                              hipStream_t stream)
{
    const float* pred    = (const float*)d_in[0];
    const int*   adj_idx = (const int*)d_in[1];
    const float* adj_w   = (const float*)d_in[2];
    const float* tevT    = (const float*)d_in[3];
    const float* tevw    = (const float*)d_in[4];
    float* out = (float*)d_out;

    const int B = 16;
    const int n = in_sizes[0] / (3 * B);
    const int maxd = in_sizes[1] / n;

    int nblk_full = (n + NT - 1) / NT;
    int ws_floats = (int)(ws_size / sizeof(float));
    float* partials = (float*)d_ws;

    if (maxd == 6 && (long long)nblk_full * B <= ws_floats) {
        dim3 grid(nblk_full, NBSPLIT);
        arap_fused6<<<grid, NT, 0, stream>>>(pred, adj_idx, adj_w, tevT,
                                             partials, n, nblk_full);
        arap_reduce<<<B, NT, 0, stream>>>(partials, out, nblk_full,
                                          1.0f / (float)n);
    } else {
        int nblk_x = nblk_full;
        if ((long long)nblk_x * B > ws_floats) nblk_x = ws_floats / B;
        if (nblk_x < 1) nblk_x = 1;
        dim3 grid(nblk_x, B);
        arap_main<<<grid, NT, 0, stream>>>(pred, adj_idx, adj_w, tevT, tevw,
                                           partials, n, maxd, nblk_x);
        arap_reduce<<<B, NT, 0, stream>>>(partials, out, nblk_x,
                                          1.0f / (float)n);
    }
}

// Round 8
// 34.862 us; speedup vs baseline: 1.5340x; 1.5340x over previous
//
#include <hip/hip_runtime.h>
#include <math.h>

#define NT 256
#define NBSPLIT 4
#define NB (16 / NBSPLIT)
#define NSWEEPS 4   // fallback kernel only

__device__ __forceinline__ float fsqrt_(float x) { return __builtin_amdgcn_sqrtf(x); }
__device__ __forceinline__ float frcp_(float x)  { return __builtin_amdgcn_rcpf(x); }
__device__ __forceinline__ float frsq_(float x)  { return __builtin_amdgcn_rsqf(x); }

// (fallback-only) cyclic-Jacobi rotation, 3-transcendental form.
__device__ __forceinline__ void jrot(float& app, float& aqq, float& apq,
                                     float& arp, float& arq,
                                     float& vp0, float& vp1, float& vp2,
                                     float& vq0, float& vq1, float& vq2)
{
    float a = apq;
    float scale = fabsf(app) + fabsf(aqq);
    if (fabsf(a) > 1e-12f * scale + 1e-35f) {
        float h = aqq - app;
        float r = fsqrt_(fmaf(h, h, 4.0f * a * a));
        float den = fabsf(h) + r;
        float t2a = (h >= 0.0f) ? 2.0f * a : -2.0f * a;
        float t = t2a * frcp_(den);
        float c = frsq_(fmaf(t, t, 1.0f));
        float s = t * c;
        app -= t * a;
        aqq += t * a;
        apq = 0.0f;
        float rp = arp, rq = arq;
        arp = c * rp - s * rq;
        arq = s * rp + c * rq;
        float x, y;
        x = vp0; y = vq0; vp0 = c * x - s * y; vq0 = s * x + c * y;
        x = vp1; y = vq1; vp1 = c * x - s * y; vq1 = s * x + c * y;
        x = vp2; y = vq2; vp2 = c * x - s * y; vq2 = s * x + c * y;
    }
}

// maxd==6 specialized, POLAR-NEWTON version (no eigensolve).
// For det(A)>0 (all but ~2 degenerate corner vertices), the reference's
// R = U diag(1,1,det) V^T IS the orthogonal polar factor of A; compute it
// with Higham scaled Newton: X0 = A/||A||F; X <- 0.5*(mu*X + (1/mu)*C/det)
// (C = cofactor matrix, X^{-T} = C/det). 3 scaled + 2 unscaled iters
// -> sigma error < 5e-5 at kappa ~ 1e4. stab=1000 cancels (scale-invariant).
// Degenerate det~0: NaN -> fminf(NaN,1)=1, error <= 2/n. ~280 VALU + 14
// trans per batch vs Jacobi path's ~466 + 39, and ~half the serial chain.
// Edges cached in regs across both passes (polar freed M/V live range).
// NO launch_bounds min-waves pin (r4/r5: catastrophic spill).
__global__ __launch_bounds__(NT) void arap_fused6(
    const float* __restrict__ pred,      // (B, 3, n)
    const int*   __restrict__ adj_idx,   // (n, 6)
    const float* __restrict__ adj_w,     // (n, 6)
    const float* __restrict__ tevT,      // (n, 3, 6)
    float* __restrict__ partials,        // (B, nblk_x)
    int n, int nblk_x)
{
    __shared__ float tvs[18][NT];        // thread-private column, no barriers
    __shared__ float sm[NT / 64][NB];

    const int tid = threadIdx.x;
    const int v = blockIdx.x * NT + tid;
    const bool active = (v < n);
    const int vc = active ? v : 0;
    const int b0 = blockIdx.y * NB;

    int   jo[6];
    float wgt[6];
    {
        const int2* ai = (const int2*)(adj_idx + (size_t)vc * 6);
        int2 q0 = ai[0], q1 = ai[1], q2 = ai[2];
        jo[0] = q0.x; jo[1] = q0.y; jo[2] = q1.x;
        jo[3] = q1.y; jo[4] = q2.x; jo[5] = q2.y;
        const float2* aw = (const float2*)(adj_w + (size_t)vc * 6);
        float2 w0 = aw[0], w1 = aw[1], w2 = aw[2];
        wgt[0] = w0.x; wgt[1] = w0.y; wgt[2] = w1.x;
        wgt[3] = w1.y; wgt[4] = w2.x; wgt[5] = w2.y;
        const float2* tv = (const float2*)(tevT + (size_t)vc * 18);
        #pragma unroll
        for (int i = 0; i < 9; ++i) {
            float2 t = tv[i];
            tvs[2 * i][tid]     = t.x;
            tvs[2 * i + 1][tid] = t.y;
        }
    }

    const int lane = tid & 63, wid = tid >> 6;

    #pragma unroll 1
    for (int bi = 0; bi < NB; ++bi) {
        const float* __restrict__ predb = pred + (size_t)(b0 + bi) * 3 * n;
        const float p0x = predb[vc];
        const float p0y = predb[n + vc];
        const float p0z = predb[2 * n + vc];

        // Pass 1: gather edges (cached for pass 2), A = pred_ev @ (w*tevT^T)
        float ex[6], ey[6], ez[6];
        float a00 = 0.f, a01 = 0.f, a02 = 0.f;
        float a10 = 0.f, a11 = 0.f, a12 = 0.f;
        float a20 = 0.f, a21 = 0.f, a22 = 0.f;
        #pragma unroll
        for (int k = 0; k < 6; ++k) {
            int j = jo[k];
            float exk = predb[j]         - p0x;
            float eyk = predb[n + j]     - p0y;
            float ezk = predb[2 * n + j] - p0z;
            ex[k] = exk; ey[k] = eyk; ez[k] = ezk;
            float t0 = tvs[k][tid], t1 = tvs[6 + k][tid], t2 = tvs[12 + k][tid];
            float w = wgt[k];
            float fx = w * exk, fy = w * eyk, fz = w * ezk;
            a00 += fx * t0; a01 += fx * t1; a02 += fx * t2;
            a10 += fy * t0; a11 += fy * t1; a12 += fy * t2;
            a20 += fz * t0; a21 += fz * t1; a22 += fz * t2;
        }

        // X0 = A / ||A||_F
        float nA = a00 * a00 + a01 * a01 + a02 * a02
                 + a10 * a10 + a11 * a11 + a12 * a12
                 + a20 * a20 + a21 * a21 + a22 * a22;
        float s0 = frsq_(nA);
        float x00 = a00 * s0, x01 = a01 * s0, x02 = a02 * s0;
        float x10 = a10 * s0, x11 = a11 * s0, x12 = a12 * s0;
        float x20 = a20 * s0, x21 = a21 * s0, x22 = a22 * s0;

        // 3 Higham-scaled Newton iterations
        #pragma unroll
        for (int it = 0; it < 3; ++it) {
            float c00 = x11 * x22 - x21 * x12;
            float c01 = x12 * x20 - x10 * x22;
            float c02 = x10 * x21 - x11 * x20;
            float c10 = x02 * x21 - x01 * x22;
            float c11 = x00 * x22 - x02 * x20;
            float c12 = x01 * x20 - x00 * x21;
            float c20 = x01 * x12 - x02 * x11;
            float c21 = x02 * x10 - x00 * x12;
            float c22 = x00 * x11 - x01 * x10;
            float det = x00 * c00 + x01 * c01 + x02 * c02;
            float nX = x00 * x00 + x01 * x01 + x02 * x02
                     + x10 * x10 + x11 * x11 + x12 * x12
                     + x20 * x20 + x21 * x21 + x22 * x22;
            float nC = c00 * c00 + c01 * c01 + c02 * c02
                     + c10 * c10 + c11 * c11 + c12 * c12
                     + c20 * c20 + c21 * c21 + c22 * c22;
            // mu = (||X^-1||F / ||X||F)^(1/2) = (nC/(det^2*nX))^(1/4)
            float ratio = nC * frcp_(det * det * nX);
            float mu = fsqrt_(fsqrt_(ratio));
            float f1 = 0.5f * mu;
            float f2 = 0.5f * frcp_(mu * det);
            x00 = f1 * x00 + f2 * c00;
            x01 = f1 * x01 + f2 * c01;
            x02 = f1 * x02 + f2 * c02;
            x10 = f1 * x10 + f2 * c10;
            x11 = f1 * x11 + f2 * c11;
            x12 = f1 * x12 + f2 * c12;
            x20 = f1 * x20 + f2 * c20;
            x21 = f1 * x21 + f2 * c21;
            x22 = f1 * x22 + f2 * c22;
        }
        // 2 unscaled Newton iterations (mu -> 1 near convergence)
        #pragma unroll
        for (int it = 0; it < 2; ++it) {
            float c00 = x11 * x22 - x21 * x12;
            float c01 = x12 * x20 - x10 * x22;
            float c02 = x10 * x21 - x11 * x20;
            float c10 = x02 * x21 - x01 * x22;
            float c11 = x00 * x22 - x02 * x20;
            float c12 = x01 * x20 - x00 * x21;
            float c20 = x01 * x12 - x02 * x11;
            float c21 = x02 * x10 - x00 * x12;
            float c22 = x00 * x11 - x01 * x10;
            float det = x00 * c00 + x01 * c01 + x02 * c02;
            float f2 = 0.5f * frcp_(det);
            x00 = 0.5f * x00 + f2 * c00;
            x01 = 0.5f * x01 + f2 * c01;
            x02 = 0.5f * x02 + f2 * c02;
            x10 = 0.5f * x10 + f2 * c10;
            x11 = 0.5f * x11 + f2 * c11;
            x12 = 0.5f * x12 + f2 * c12;
            x20 = 0.5f * x20 + f2 * c20;
            x21 = 0.5f * x21 + f2 * c21;
            x22 = 0.5f * x22 + f2 * c22;
        }
        // R = X (orthogonal polar factor)

        // Pass 2: energy from cached edges
        float nrg = 0.0f;
        #pragma unroll
        for (int k = 0; k < 6; ++k) {
            float t0 = tvs[k][tid], t1 = tvs[6 + k][tid], t2 = tvs[12 + k][tid];
            float q0 = x00 * t0 + x01 * t1 + x02 * t2;
            float q1 = x10 * t0 + x11 * t1 + x12 * t2;
            float q2 = x20 * t0 + x21 * t1 + x22 * t2;
            float dx = ex[k] - q0, dy = ey[k] - q1, dz = ez[k] - q2;
            nrg += wgt[k] * fsqrt_(dx * dx + dy * dy + dz * dz);
        }
        float val = active ? fminf(nrg, 1.0f) : 0.0f;  // fminf(NaN,1)=1: bounds degenerate verts

        #pragma unroll
        for (int off = 32; off > 0; off >>= 1)
            val += __shfl_down(val, off, 64);
        if (lane == 0) sm[wid][bi] = val;
    }

    __syncthreads();
    if (tid < NB) {
        float s = 0.0f;
        #pragma unroll
        for (int w = 0; w < NT / 64; ++w) s += sm[w][tid];
        partials[(size_t)(b0 + tid) * nblk_x + blockIdx.x] = s;
    }
}

// ---------------- generic fallback (Jacobi path, unchanged) ----------------
__global__ __launch_bounds__(NT) void arap_main(
    const float* __restrict__ pred, const int* __restrict__ adj_idx,
    const float* __restrict__ adj_w, const float* __restrict__ tevT,
    const float* __restrict__ tevw, float* __restrict__ partials,
    int n, int maxd, int nblk_x)
{
    const int b = blockIdx.y;
    const float* __restrict__ predb = pred + (size_t)b * 3 * n;
    float local = 0.0f;

    for (int v = blockIdx.x * NT + threadIdx.x; v < n; v += nblk_x * NT) {
        const float p0x = predb[v];
        const float p0y = predb[n + v];
        const float p0z = predb[2 * n + v];

        float a00 = 0.f, a01 = 0.f, a02 = 0.f;
        float a10 = 0.f, a11 = 0.f, a12 = 0.f;
        float a20 = 0.f, a21 = 0.f, a22 = 0.f;
        for (int k = 0; k < maxd; ++k) {
            int j = adj_idx[v * maxd + k];
            float ex = predb[j] - p0x;
            float ey = predb[n + j] - p0y;
            float ez = predb[2 * n + j] - p0z;
            const float* tw = tevw + ((size_t)v * maxd + k) * 3;
            float t0 = tw[0], t1 = tw[1], t2 = tw[2];
            a00 += ex * t0; a01 += ex * t1; a02 += ex * t2;
            a10 += ey * t0; a11 += ey * t1; a12 += ey * t2;
            a20 += ez * t0; a21 += ez * t1; a22 += ez * t2;
        }
        const float stab = 1000.0f;
        a00 *= stab; a01 *= stab; a02 *= stab;
        a10 *= stab; a11 *= stab; a12 *= stab;
        a20 *= stab; a21 *= stab; a22 *= stab;

        float m00 = a00 * a00 + a10 * a10 + a20 * a20;
        float m01 = a00 * a01 + a10 * a11 + a20 * a21;
        float m02 = a00 * a02 + a10 * a12 + a20 * a22;
        float m11 = a01 * a01 + a11 * a11 + a21 * a21;
        float m12 = a01 * a02 + a11 * a12 + a21 * a22;
        float m22 = a02 * a02 + a12 * a12 + a22 * a22;

        float v00 = 1.f, v01 = 0.f, v02 = 0.f;
        float v10 = 0.f, v11 = 1.f, v12 = 0.f;
        float v20 = 0.f, v21 = 0.f, v22 = 1.f;
        #pragma unroll
        for (int sweep = 0; sweep < NSWEEPS; ++sweep) {
            jrot(m00, m11, m01, m02, m12, v00, v10, v20, v01, v11, v21);
            jrot(m00, m22, m02, m01, m12, v00, v10, v20, v02, v12, v22);
            jrot(m11, m22, m12, m01, m02, v01, v11, v21, v02, v12, v22);
        }

        float is0 = frsq_(fmaxf(m00, 1e-6f));
        float is1 = frsq_(fmaxf(m11, 1e-6f));
        float is2 = frsq_(fmaxf(m22, 1e-6f));
        float detA = a00 * (a11 * a22 - a21 * a12)
                   - a10 * (a01 * a22 - a21 * a02)
                   + a20 * (a01 * a12 - a11 * a02);
        float dd = detA * is0 * is1 * is2;
        bool c2 = (m22 >= m00) && (m22 >= m11);
        bool c1 = !c2 && (m11 >= m00);
        bool c0 = !c2 && !c1;
        is0 = c0 ? is0 * dd : is0;
        is1 = c1 ? is1 * dd : is1;
        is2 = c2 ? is2 * dd : is2;

        float w00 = is0 * v00 * v00 + is1 * v01 * v01 + is2 * v02 * v02;
        float w01 = is0 * v00 * v10 + is1 * v01 * v11 + is2 * v02 * v12;
        float w02 = is0 * v00 * v20 + is1 * v01 * v21 + is2 * v02 * v22;
        float w11 = is0 * v10 * v10 + is1 * v11 * v11 + is2 * v12 * v12;
        float w12 = is0 * v10 * v20 + is1 * v11 * v21 + is2 * v12 * v22;
        float w22 = is0 * v20 * v20 + is1 * v21 * v21 + is2 * v22 * v22;

        float r00 = a00 * w00 + a01 * w01 + a02 * w02;
        float r01 = a00 * w01 + a01 * w11 + a02 * w12;
        float r02 = a00 * w02 + a01 * w12 + a02 * w22;
        float r10 = a10 * w00 + a11 * w01 + a12 * w02;
        float r11 = a10 * w01 + a11 * w11 + a12 * w12;
        float r12 = a10 * w02 + a11 * w12 + a12 * w22;
        float r20 = a20 * w00 + a21 * w01 + a22 * w02;
        float r21 = a20 * w01 + a21 * w11 + a22 * w12;
        float r22 = a20 * w02 + a21 * w12 + a22 * w22;

        float nrg = 0.0f;
        const float* tvb = tevT + (size_t)v * 3 * maxd;
        for (int k = 0; k < maxd; ++k) {
            int j = adj_idx[v * maxd + k];
            float w = adj_w[v * maxd + k];
            float ex = predb[j] - p0x;
            float ey = predb[n + j] - p0y;
            float ez = predb[2 * n + j] - p0z;
            float tv0 = tvb[k];
            float tv1 = tvb[maxd + k];
            float tv2 = tvb[2 * maxd + k];
            float q0 = r00 * tv0 + r01 * tv1 + r02 * tv2;
            float q1 = r10 * tv0 + r11 * tv1 + r12 * tv2;
            float q2 = r20 * tv0 + r21 * tv1 + r22 * tv2;
            float dx = ex - q0, dy = ey - q1, dz = ez - q2;
            nrg += w * fsqrt_(dx * dx + dy * dy + dz * dz);
        }
        local += fminf(nrg, 1.0f);
    }

    float val = local;
    for (int off = 32; off > 0; off >>= 1)
        val += __shfl_down(val, off, 64);
    __shared__ float smf[NT / 64];
    int lane = threadIdx.x & 63, wid = threadIdx.x >> 6;
    if (lane == 0) smf[wid] = val;
    __syncthreads();
    if (threadIdx.x == 0)
        partials[(size_t)b * nblk_x + blockIdx.x] = smf[0] + smf[1] + smf[2] + smf[3];
}

__global__ __launch_bounds__(NT) void arap_reduce(
    const float* __restrict__ partials, float* __restrict__ out,
    int nblk_x, float inv_n)
{
    int b = blockIdx.x;
    float val = 0.0f;
    for (int i = threadIdx.x; i < nblk_x; i += NT)
        val += partials[(size_t)b * nblk_x + i];
    for (int off = 32; off > 0; off >>= 1)
        val += __shfl_down(val, off, 64);
    __shared__ float smf[NT / 64];
    int lane = threadIdx.x & 63, wid = threadIdx.x >> 6;
    if (lane == 0) smf[wid] = val;
    __syncthreads();
    if (threadIdx.x == 0)
        out[b] = (smf[0] + smf[1] + smf[2] + smf[3]) * inv_n;
}

extern "C" void kernel_launch(void* const* d_in, const int* in_sizes, int n_in,
                              void* d_out, int out_size, void* d_ws, size_t ws_size,
                              hipStream_t stream)
{
    const float* pred    = (const float*)d_in[0];
    const int*   adj_idx = (const int*)d_in[1];
    const float* adj_w   = (const float*)d_in[2];
    const float* tevT    = (const float*)d_in[3];
    const float* tevw    = (const float*)d_in[4];
    float* out = (float*)d_out;

    const int B = 16;
    const int n = in_sizes[0] / (3 * B);
    const int maxd = in_sizes[1] / n;

    int nblk_full = (n + NT - 1) / NT;
    int ws_floats = (int)(ws_size / sizeof(float));
    float* partials = (float*)d_ws;

    if (maxd == 6 && (long long)nblk_full * B <= ws_floats) {
        dim3 grid(nblk_full, NBSPLIT);
        arap_fused6<<<grid, NT, 0, stream>>>(pred, adj_idx, adj_w, tevT,
                                             partials, n, nblk_full);
        arap_reduce<<<B, NT, 0, stream>>>(partials, out, nblk_full,
                                          1.0f / (float)n);
    } else {
        int nblk_x = nblk_full;
        if ((long long)nblk_x * B > ws_floats) nblk_x = ws_floats / B;
        if (nblk_x < 1) nblk_x = 1;
        dim3 grid(nblk_x, B);
        arap_main<<<grid, NT, 0, stream>>>(pred, adj_idx, adj_w, tevT, tevw,
                                           partials, n, maxd, nblk_x);
        arap_reduce<<<B, NT, 0, stream>>>(partials, out, nblk_x,
                                          1.0f / (float)n);
    }
}